// Round 6
// baseline (2740.519 us; speedup 1.0000x reference)
//
#include <hip/hip_runtime.h>
#include <cstdint>

// ---------------------------------------------------------------------------
// MaskedDeepRNN fused v6: 2-layer masked LSTM, B=64 T=512 D_IN=256 H=512.
// 256 WGs x 576 thr (9 waves, 1/CU). blocks 0..127 layer 0, 128..255 layer 1;
// isl = bid&7 (XCD), wgm = (bid>>3)&15 (16 WGs/island own 32 units each).
// Wave-specialized, barrier-free T-loop:
//   wave 8 (comm): poll flags -> bulk gather rings/x -> LDS scatter ->
//                  ready[par]=t+1 -> spin done[0..7]>=t+1 -> publish WG flag.
//   waves 0..7 (compute): spin ready -> MFMA (own 4 units x 4 gates, FULL K,
//                  no cross-wave reduction) -> in-wave LDS transpose ->
//                  gates/cell -> ONE 64B ring line store -> vmcnt(0) ->
//                  done[w]=t+1.
// Ring layout unit-major: u32 idx = wg*128 + w*16 + u2*8 + b  (full-line
// per-wave stores; v4's partial-line writeback regression avoided).
// ---------------------------------------------------------------------------

typedef _Float16 f16;
typedef _Float16 half8 __attribute__((ext_vector_type(8)));
typedef _Float16 half4v __attribute__((ext_vector_type(4)));
typedef float floatx4 __attribute__((ext_vector_type(4)));
typedef unsigned long long u64;

#define B_ 64
#define T_ 512
#define DIN_ 256
#define H_ 512
#define G_ 2048

// workspace layout (bytes)
static const size_t OFF_FLAGS = 0;                         // 2x8x16 x 64B = 16 KB
static const size_t OFF_H0B   = 16384;                     // 8 isl x 4 slots x 8KB = 256 KB
static const size_t OFF_H1B   = OFF_H0B + 262144;          // 256 KB
static const size_t OFF_XT    = OFF_H1B + 262144;          // 16 MB x f16 [t*64+b][256]
static const size_t OFF_WIH0  = OFF_XT + 16777216;
static const size_t OFF_WHH0  = OFF_WIH0 + (size_t)G_ * DIN_ * 2;
static const size_t OFF_WIH1  = OFF_WHH0 + (size_t)G_ * H_ * 2;
static const size_t OFF_WHH1  = OFF_WIH1 + (size_t)G_ * H_ * 2;
static const size_t OFF_B0    = OFF_WHH1 + (size_t)G_ * H_ * 2;
static const size_t OFF_B1    = OFF_B0 + 8192;
static const size_t ZERO_BYTES = OFF_XT;                   // flags + rings

__device__ __forceinline__ uint32_t ald(const uint32_t* p) {
    return __hip_atomic_load(p, __ATOMIC_RELAXED, __HIP_MEMORY_SCOPE_AGENT);
}
__device__ __forceinline__ void ast(uint32_t* p, uint32_t v) {
    __hip_atomic_store(p, v, __ATOMIC_RELAXED, __HIP_MEMORY_SCOPE_AGENT);
}
__device__ __forceinline__ u64 ald64(const u64* p) {
    return __hip_atomic_load(p, __ATOMIC_RELAXED, __HIP_MEMORY_SCOPE_AGENT);
}
__device__ __forceinline__ uint32_t ldsld(const uint32_t* p) {
    return __hip_atomic_load(p, __ATOMIC_RELAXED, __HIP_MEMORY_SCOPE_WORKGROUP);
}
__device__ __forceinline__ void ldsst(uint32_t* p, uint32_t v) {
    __hip_atomic_store(p, v, __ATOMIC_RELAXED, __HIP_MEMORY_SCOPE_WORKGROUP);
}

// ---------------------------------------------------------------- prep ------
__global__ void k_maskw(const float* __restrict__ w, const float* __restrict__ m,
                        f16* __restrict__ o, int n4) {
    int i = blockIdx.x * 256 + threadIdx.x;
    if (i < n4) {
        const float4 wv = ((const float4*)w)[i];
        const float4 mv = ((const float4*)m)[i];
        half4v h = { (f16)(wv.x * mv.x), (f16)(wv.y * mv.y),
                     (f16)(wv.z * mv.z), (f16)(wv.w * mv.w) };
        ((half4v*)o)[i] = h;
    }
}

__global__ void k_bias(const float* __restrict__ a, const float* __restrict__ b,
                       float* __restrict__ o) {
    int i = blockIdx.x * 256 + threadIdx.x;
    if (i < G_) o[i] = a[i] + b[i];
}

// x [b][t][k] fp32 -> xt [(t*64+b)][k] f16
__global__ void k_xt(const float* __restrict__ x, f16* __restrict__ xt) {
    const int idx = blockIdx.x * 256 + threadIdx.x;  // 2097152 total, 4 elems each
    const int k4 = idx & 63;
    const int t  = (idx >> 6) & 511;
    const int b  = idx >> 15;
    const float4 v = *(const float4*)(x + (((size_t)b * T_ + t) * DIN_) + k4 * 4);
    half4v h = { (f16)v.x, (f16)v.y, (f16)v.z, (f16)v.w };
    *(half4v*)(xt + ((size_t)t * B_ + b) * DIN_ + k4 * 4) = h;
}

// ------------------------------------------------------------ helpers -------
__device__ __forceinline__ float lstm_cell(float gi, float gf, float gg, float go,
                                           float& c) {
    const float i_ = 1.f / (1.f + __expf(-gi));
    const float f_ = 1.f / (1.f + __expf(-gf));
    const float gc = fminf(fmaxf(gg, -20.f), 20.f);
    const float e2 = __expf(2.f * gc);
    const float g_ = (e2 - 1.f) / (e2 + 1.f);
    const float o_ = 1.f / (1.f + __expf(-go));
    c = f_ * c + i_ * g_;
    const float cc  = fminf(fmaxf(c, -20.f), 20.f);
    const float e2c = __expf(2.f * cc);
    return o_ * (e2c - 1.f) / (e2c + 1.f);
}

// -------------------------------------------------------- fused kernel ------
// Compute wave w owns units uw = wgm*32 + w*4 .. +4. A-rows (16): r16 = lm ->
// gate gt = lm>>2, unit-in-wave ju = lm&3, row = gt*512 + uw + ju. C-layout:
// acc[r] at lane(quad,lm): r16 = quad*4+r, batch = lm (lm<8 valid).
__global__ __launch_bounds__(576, 1) void fused_rnn(
    const f16* __restrict__ xt,
    const f16* __restrict__ Wih0, const f16* __restrict__ Whh0,
    const float* __restrict__ bs0,
    const f16* __restrict__ Wih1, const f16* __restrict__ Whh1,
    const float* __restrict__ bs1,
    float* __restrict__ dout,
    uint32_t* __restrict__ h0b,      // [8 isl][4 slots][2048 u32] unit-major
    uint32_t* __restrict__ h1b,
    uint32_t* __restrict__ flags)    // [2 lay][8 isl][16 WG][16 u32]
{
    __shared__ f16 bl0[2][8][520];         // own-layer h[t-1] (parity by t)
    __shared__ f16 bl1[2][8][520];         // x[t] (L0) / h0[t] (L1)
    __shared__ float tw[8][16][9];         // per-wave transpose scratch
    __shared__ uint32_t ready[2];          // staged-step tokens (t+1)
    __shared__ uint32_t done[8];           // per-compute-wave step tokens

    const int tid  = threadIdx.x;
    const int bid  = blockIdx.x;
    const int isl  = bid & 7;
    const int wgm  = (bid >> 3) & 15;
    const int layer = bid >> 7;
    const int b0 = isl * 8;
    const int wave = tid >> 6, lane = tid & 63, lm = lane & 15, quad = lane >> 4;
    const int hrow = lm < 8 ? lm : 7;
    const int uw = wgm * 32 + wave * 4;

    uint32_t* ownF   = flags + (size_t)(layer * 8 + isl) * 256;
    uint32_t* crossF = flags + (size_t)((1 - layer) * 8 + isl) * 256;
    uint32_t* myF    = ownF + wgm * 16;
    const uint32_t* fpp = ((lane & 31) < 16)
        ? ownF + (size_t)(lane & 15) * 16
        : crossF + (size_t)(lane & 15) * 16;
    const bool pollOwn = (lane & 31) < 16;

    uint32_t* h0i = h0b + (size_t)isl * 4 * 2048;
    uint32_t* h1i = h1b + (size_t)isl * 4 * 2048;
    uint32_t* ring   = (layer == 0) ? h0i : h1i;
    const u64* ringu  = (const u64*)ring;
    const u64* crossu = (const u64*)h0i;

    if (tid == 0) { ready[0] = 0; ready[1] = 0; }
    if (tid < 8) done[tid] = 0;
    __syncthreads();                       // one-time init barrier

    if (wave == 8) {
        // ================= comm wave =================
        for (int t = 0; t < T_; ++t) {
            const int par = t & 1;
            // ---- poll: own island flags >= t; cross per layer
            {
                const uint32_t tgt = pollOwn ? (uint32_t)t
                    : (layer == 0 ? (t >= 3 ? (uint32_t)(t - 3) : 0u)
                                  : (uint32_t)(t + 1));
                uint32_t v = ald(fpp);
                while (!__all((int)(v >= tgt))) {
                    __builtin_amdgcn_s_sleep(1);
                    v = ald(fpp);
                }
            }
            // ---- gather own ring slot (t-1)&3 (h[t-1]), 16 u64/lane
            const u64* sp = ringu + (size_t)((t + 3) & 3) * 1024;
            u64 rv[16];
#pragma unroll
            for (int i = 0; i < 16; ++i) rv[i] = ald64(sp + i * 64 + lane);
            if (layer == 0) {
                // x[t] slice: 8 u64/lane from xt
                const u64* xr = (const u64*)xt + (size_t)(t * B_ + b0) * 64;
                u64 xv[8];
#pragma unroll
                for (int i = 0; i < 8; ++i) xv[i] = *(xr + i * 64 + lane);
#pragma unroll
                for (int i = 0; i < 16; ++i) {
                    const int j = i * 64 + lane;
                    const int u2g = j >> 2, bp = (j & 3) * 2;
                    *(uint32_t*)&bl0[par][bp][2 * u2g]     = (uint32_t)rv[i];
                    *(uint32_t*)&bl0[par][bp + 1][2 * u2g] = (uint32_t)(rv[i] >> 32);
                }
#pragma unroll
                for (int i = 0; i < 8; ++i) {
                    const int j = i * 64 + lane;
                    *(u64*)&bl1[par][j >> 6][(j & 63) * 4] = xv[i];
                }
            } else {
                // cross: h0[t] slot t&3
                const u64* cp = crossu + (size_t)(t & 3) * 1024;
                u64 cv[16];
#pragma unroll
                for (int i = 0; i < 16; ++i) cv[i] = ald64(cp + i * 64 + lane);
#pragma unroll
                for (int i = 0; i < 16; ++i) {
                    const int j = i * 64 + lane;
                    const int u2g = j >> 2, bp = (j & 3) * 2;
                    *(uint32_t*)&bl0[par][bp][2 * u2g]     = (uint32_t)rv[i];
                    *(uint32_t*)&bl0[par][bp + 1][2 * u2g] = (uint32_t)(rv[i] >> 32);
                    *(uint32_t*)&bl1[par][bp][2 * u2g]     = (uint32_t)cv[i];
                    *(uint32_t*)&bl1[par][bp + 1][2 * u2g] = (uint32_t)(cv[i] >> 32);
                }
            }
            asm volatile("s_waitcnt lgkmcnt(0)" ::: "memory");
            if (lane == 0) ldsst(&ready[par], (uint32_t)(t + 1));
            // ---- wait own compute waves, then publish WG flag
            {
                uint32_t dv = ldsld(&done[lane & 7]);
                while (!__all((int)(dv >= (uint32_t)(t + 1)))) {
                    __builtin_amdgcn_s_sleep(1);
                    dv = ldsld(&done[lane & 7]);
                }
            }
            if (lane == 0) ast(myF, (uint32_t)(t + 1));
        }
        return;
    }

    // ================= compute waves 0..7 =================
    const int gb = lane >> 2, gju = lane & 3;      // gate phase (lane<32)
    float bias[4];
    {
        const float* bsrc = (layer == 0) ? bs0 : bs1;
#pragma unroll
        for (int g = 0; g < 4; ++g) bias[g] = bsrc[g * 512 + uw + gju];
    }
    float c = 0.f;
    const int wrow = (lm >> 2) * 512 + uw + (lm & 3);   // this lane's A row
    const f16* whp = ((layer == 0) ? Whh0 : Whh1) + (size_t)wrow * H_ + quad * 8;
    const f16* wip = (layer == 0) ? (Wih0 + (size_t)wrow * DIN_ + quad * 8)
                                  : (Wih1 + (size_t)wrow * H_ + quad * 8);

    for (int t = 0; t < T_; ++t) {
        const int par = t & 1;
        // ---- wait staged inputs
        {
            uint32_t r = ldsld(&ready[par]);
            while (r < (uint32_t)(t + 1)) {
                __builtin_amdgcn_s_sleep(1);
                r = ldsld(&ready[par]);
            }
        }
        // ---- MFMA: own 4 units x 4 gates, full K
        floatx4 a0 = {}, a1 = {};
        {
            const f16* br0 = &bl0[par][hrow][quad * 8];
            const f16* br1 = &bl1[par][hrow][quad * 8];
#pragma unroll
            for (int kk = 0; kk < 16; ++kk)
                a0 = __builtin_amdgcn_mfma_f32_16x16x32_f16(
                    *(const half8*)(whp + kk * 32),
                    *(const half8*)(br0 + kk * 32), a0, 0, 0, 0);
            const int nki = (layer == 0) ? 8 : 16;
#pragma unroll
            for (int kk = 0; kk < 16; ++kk) {
                if (kk < nki)
                    a1 = __builtin_amdgcn_mfma_f32_16x16x32_f16(
                        *(const half8*)(wip + kk * 32),
                        *(const half8*)(br1 + kk * 32), a1, 0, 0, 0);
            }
        }
        const floatx4 acc = a0 + a1;
        // ---- in-wave transpose (no barrier)
        if (lm < 8)
#pragma unroll
            for (int r = 0; r < 4; ++r) tw[wave][quad * 4 + r][lm] = acc[r];
        asm volatile("s_waitcnt lgkmcnt(0)" ::: "memory");
        if (lane < 32) {
            const float gi = bias[0] + tw[wave][0 * 4 + gju][gb];
            const float gf = bias[1] + tw[wave][1 * 4 + gju][gb];
            const float gg = bias[2] + tw[wave][2 * 4 + gju][gb];
            const float go = bias[3] + tw[wave][3 * 4 + gju][gb];
            const float hn = lstm_cell(gi, gf, gg, go, c);
            const float ho = __shfl_xor(hn, 1);
            if (!(gju & 1)) {
                union { f16 h[2]; uint32_t u; } pk;
                pk.h[0] = (f16)hn; pk.h[1] = (f16)ho;
                ast(ring + (size_t)(t & 3) * 2048 + wgm * 128 + wave * 16
                         + (gju >> 1) * 8 + gb, pk.u);
            }
            if (layer == 1 && t == T_ - 1)
                dout[(size_t)(b0 + gb) * H_ + uw + gju] = hn;
        }
        asm volatile("s_waitcnt vmcnt(0)" ::: "memory");
        if (lane == 0) ldsst(&done[wave], (uint32_t)(t + 1));
    }
}

// ------------------------------------------------------------ launcher ------
extern "C" void kernel_launch(void* const* d_in, const int* in_sizes, int n_in,
                              void* d_out, int out_size, void* d_ws, size_t ws_size,
                              hipStream_t stream) {
    const float* x    = (const float*)d_in[0];
    const float* Wih0 = (const float*)d_in[1];
    const float* Whh0 = (const float*)d_in[2];
    const float* bih0 = (const float*)d_in[3];
    const float* bhh0 = (const float*)d_in[4];
    const float* mih0 = (const float*)d_in[5];
    const float* mhh0 = (const float*)d_in[6];
    const float* Wih1 = (const float*)d_in[7];
    const float* Whh1 = (const float*)d_in[8];
    const float* bih1 = (const float*)d_in[9];
    const float* bhh1 = (const float*)d_in[10];
    const float* mih1 = (const float*)d_in[11];
    const float* mhh1 = (const float*)d_in[12];

    char* ws = (char*)d_ws;
    uint32_t* flags = (uint32_t*)(ws + OFF_FLAGS);
    uint32_t* h0b = (uint32_t*)(ws + OFF_H0B);
    uint32_t* h1b = (uint32_t*)(ws + OFF_H1B);
    f16*   xt   = (f16*)(ws + OFF_XT);
    f16*   wih0 = (f16*)(ws + OFF_WIH0);
    f16*   whh0 = (f16*)(ws + OFF_WHH0);
    f16*   wih1 = (f16*)(ws + OFF_WIH1);
    f16*   whh1 = (f16*)(ws + OFF_WHH1);
    float* bs0  = (float*)(ws + OFF_B0);
    float* bs1  = (float*)(ws + OFF_B1);
    float* out  = (float*)d_out;

    hipMemsetAsync(ws, 0, ZERO_BYTES, stream);   // flags + rings must start 0

    k_maskw<<<512,  256, 0, stream>>>(Wih0, mih0, wih0, G_ * DIN_ / 4);
    k_maskw<<<1024, 256, 0, stream>>>(Whh0, mhh0, whh0, G_ * H_ / 4);
    k_maskw<<<1024, 256, 0, stream>>>(Wih1, mih1, wih1, G_ * H_ / 4);
    k_maskw<<<1024, 256, 0, stream>>>(Whh1, mhh1, whh1, G_ * H_ / 4);
    k_bias<<<8, 256, 0, stream>>>(bih0, bhh0, bs0);
    k_bias<<<8, 256, 0, stream>>>(bih1, bhh1, bs1);
    k_xt<<<8192, 256, 0, stream>>>(x, xt);

    fused_rnn<<<256, 576, 0, stream>>>(xt, wih0, whh0, bs0, wih1, whh1, bs1,
                                       out, h0b, h1b, flags);

    (void)in_sizes; (void)n_in; (void)out_size; (void)ws_size;
}

// Round 7
// 1432.474 us; speedup vs baseline: 1.9131x; 1.9131x over previous
//
#include <hip/hip_runtime.h>
#include <cstdint>

// ---------------------------------------------------------------------------
// MaskedDeepRNN fused v7 = v5 + amdgpu_waves_per_eu(2,2).
// v5 mechanics: 256 WGs x 512 thr (1/CU, 8 waves). blocks 0..127 layer 0,
// 128..255 layer 1; isl = bid&7 (XCD), wgm = (bid>>3)&15. Each WG owns 32
// hidden units: 8 waves = 2 unit-groups x 4 K-quarters.
// v7 change: pin waves/EU to exactly 2 so the register allocator may use up
// to 256 VGPR/wave at zero occupancy cost -> weight fragments actually
// PERSIST in VGPRs (v2..v6 all re-streamed ~200KB/CU/step from L2, which is
// ~1.5-1.9us/step = the observed plateau).
// ---------------------------------------------------------------------------

typedef _Float16 f16;
typedef _Float16 half8 __attribute__((ext_vector_type(8)));
typedef _Float16 half4v __attribute__((ext_vector_type(4)));
typedef float floatx4 __attribute__((ext_vector_type(4)));
typedef unsigned long long u64;

#define B_ 64
#define T_ 512
#define DIN_ 256
#define H_ 512
#define G_ 2048

// workspace layout (bytes)
static const size_t OFF_FLAGS = 0;                         // 2 lay x 8 isl x 16 WG x 64B = 16 KB
static const size_t OFF_H0B   = 16384;                     // 8 isl x 4 slots x 8KB = 256 KB
static const size_t OFF_H1B   = OFF_H0B + 262144;          // 256 KB
static const size_t OFF_WIH0  = OFF_H1B + 262144;
static const size_t OFF_WHH0  = OFF_WIH0 + (size_t)G_ * DIN_ * 2;
static const size_t OFF_WIH1  = OFF_WHH0 + (size_t)G_ * H_ * 2;
static const size_t OFF_WHH1  = OFF_WIH1 + (size_t)G_ * H_ * 2;
static const size_t OFF_B0    = OFF_WHH1 + (size_t)G_ * H_ * 2;
static const size_t OFF_B1    = OFF_B0 + 8192;
static const size_t ZERO_BYTES = OFF_WIH0;                 // flags + rings

__device__ __forceinline__ uint32_t ald(const uint32_t* p) {
    return __hip_atomic_load(p, __ATOMIC_RELAXED, __HIP_MEMORY_SCOPE_AGENT);
}
__device__ __forceinline__ void ast(uint32_t* p, uint32_t v) {
    __hip_atomic_store(p, v, __ATOMIC_RELAXED, __HIP_MEMORY_SCOPE_AGENT);
}
__device__ __forceinline__ u64 ald64(const u64* p) {
    return __hip_atomic_load(p, __ATOMIC_RELAXED, __HIP_MEMORY_SCOPE_AGENT);
}

// ---------------------------------------------------------------- prep ------
__global__ void k_maskw(const float* __restrict__ w, const float* __restrict__ m,
                        f16* __restrict__ o, int n4) {
    int i = blockIdx.x * 256 + threadIdx.x;
    if (i < n4) {
        const float4 wv = ((const float4*)w)[i];
        const float4 mv = ((const float4*)m)[i];
        half4v h = { (f16)(wv.x * mv.x), (f16)(wv.y * mv.y),
                     (f16)(wv.z * mv.z), (f16)(wv.w * mv.w) };
        ((half4v*)o)[i] = h;
    }
}

__global__ void k_bias(const float* __restrict__ a, const float* __restrict__ b,
                       float* __restrict__ o) {
    int i = blockIdx.x * 256 + threadIdx.x;
    if (i < G_) o[i] = a[i] + b[i];
}

// ------------------------------------------------------------ helpers -------
__device__ __forceinline__ float lstm_cell(float gi, float gf, float gg, float go,
                                           float& c) {
    const float i_ = 1.f / (1.f + __expf(-gi));
    const float f_ = 1.f / (1.f + __expf(-gf));
    const float gc = fminf(fmaxf(gg, -20.f), 20.f);
    const float e2 = __expf(2.f * gc);
    const float g_ = (e2 - 1.f) / (e2 + 1.f);
    const float o_ = 1.f / (1.f + __expf(-go));
    c = f_ * c + i_ * g_;
    const float cc  = fminf(fmaxf(c, -20.f), 20.f);
    const float e2c = __expf(2.f * cc);
    return o_ * (e2c - 1.f) / (e2c + 1.f);
}

// -------------------------------------------------------- fused kernel ------
// Wave (kq = wave&3, ug = wave>>2) owns units ub = wgm*32+ug*16 .. +16 at
// K-quarter kq. A-rows: gt*512 + ub + lm. C-layout: acc[gt][r] = gate gt,
// unit ub + quad*4+r, batch lm (lm<8 valid).
// Ring (u32 pairs): [slot][b][256] with WG chunk [b][wgm*16 .. +16] = 64 B.
__global__ __launch_bounds__(512)
__attribute__((amdgpu_waves_per_eu(2, 2)))
void fused_rnn(
    const float* __restrict__ x,
    const f16* __restrict__ Wih0, const f16* __restrict__ Whh0,
    const float* __restrict__ bs0,
    const f16* __restrict__ Wih1, const f16* __restrict__ Whh1,
    const float* __restrict__ bs1,
    float* __restrict__ dout,
    uint32_t* __restrict__ h0b,      // [8 isl][4 slots][2048 u32]
    uint32_t* __restrict__ h1b,
    uint32_t* __restrict__ flags)    // [2 lay][8 isl][16 WG][16 u32]
{
    __shared__ f16 bl0[2][8][520];         // own-layer h (parity by t)
    __shared__ f16 bl1[2][8][520];         // x (L0) / h0 (L1)
    __shared__ float glp[2][4][4][16][9];  // [ug][kq][gate][jj][b]

    const int tid  = threadIdx.x;
    const int bid  = blockIdx.x;
    const int isl  = bid & 7;
    const int wgm  = (bid >> 3) & 15;
    const int layer = bid >> 7;
    const int b0 = isl * 8;
    const int wave = tid >> 6, lane = tid & 63, lm = lane & 15, quad = lane >> 4;
    const int kq = wave & 3, ug = wave >> 2;
    const int ub = wgm * 32 + ug * 16;
    const int hrow = lm < 8 ? lm : 7;
    // gate phase (tid < 256): batch gb, unit-in-WG gj
    const int gb = tid >> 5, gj = tid & 31;
    const int gug = gj >> 4, gjj = gj & 15;

    uint32_t* ownF   = flags + (size_t)(layer * 8 + isl) * 256;
    uint32_t* crossF = flags + (size_t)((1 - layer) * 8 + isl) * 256;
    uint32_t* myF    = ownF + wgm * 16;
    const uint32_t* fpp = ((lane & 31) < 16)
        ? ownF + (size_t)(lane & 15) * 16
        : crossF + (size_t)(lane & 15) * 16;
    const bool pollOwn = (lane & 31) < 16;

    uint32_t* h0i = h0b + (size_t)isl * 4 * 2048;
    uint32_t* h1i = h1b + (size_t)isl * 4 * 2048;
    uint32_t* ring   = (layer == 0) ? h0i : h1i;
    const u64* ringu  = (const u64*)ring;
    const u64* crossu = (const u64*)h0i;

    float bias[4];
    {
        const float* bsrc = (layer == 0) ? bs0 : bs1;
#pragma unroll
        for (int g = 0; g < 4; ++g) bias[g] = bsrc[g * 512 + wgm * 32 + gj];
    }
    float c = 0.f;

    if (layer == 0) {
        half8 ah[4][4], ai[4][2];
        {
#pragma unroll
            for (int gt = 0; gt < 4; ++gt) {
                const f16* wr = Whh0 + (size_t)(gt * 512 + ub + lm) * H_
                              + kq * 128 + quad * 8;
                const f16* xr = Wih0 + (size_t)(gt * 512 + ub + lm) * DIN_
                              + kq * 64 + quad * 8;
#pragma unroll
                for (int kk = 0; kk < 4; ++kk) ah[gt][kk] = *(const half8*)(wr + kk * 32);
#pragma unroll
                for (int kk = 0; kk < 2; ++kk) ai[gt][kk] = *(const half8*)(xr + kk * 32);
            }
        }
        // x slice: thread -> (batch = tid>>6, k4 = (tid&63)*4)
        const float* xp = x + (size_t)(b0 + (tid >> 6)) * T_ * DIN_ + (tid & 63) * 4;
        float4 xa = *(const float4*)xp;        // x[0]

        for (int t = 0; t < T_; ++t) {
            const int par = t & 1;
            // ---- poll: own >= t, L1 back-pressure >= t-3
            if (wave == 0) {
                const uint32_t tgt = pollOwn ? (uint32_t)t
                                   : (t >= 3 ? (uint32_t)(t - 3) : 0u);
                uint32_t v = ald(fpp);
                while (!__all((int)(v >= tgt))) {
                    __builtin_amdgcn_s_sleep(1);
                    v = ald(fpp);
                }
            }
            __syncthreads();
            // ---- bulk gather h0[t-1] (slot (t-1)&3): 2 u64/thread, coalesced
            {
                const u64* sp = ringu + (size_t)((t + 3) & 3) * 1024;
                const u64 v0 = ald64(sp + tid);
                const u64 v1 = ald64(sp + 512 + tid);
                // x[t] -> bl1, prefetch x[t+1]
                half4v hx = { (f16)xa.x, (f16)xa.y, (f16)xa.z, (f16)xa.w };
                *(half4v*)&bl1[par][tid >> 6][(tid & 63) * 4] = hx;
                const size_t tn = (size_t)(t + 1 < T_ ? t + 1 : t) * DIN_;
                xa = *(const float4*)(xp + tn);
                *(u64*)&bl0[par][tid >> 7][(tid & 127) * 4] = v0;
                *(u64*)&bl0[par][(tid >> 7) + 4][(tid & 127) * 4] = v1;
            }
            __syncthreads();
            // ---- MFMA: 16 Whh + 8 Wih per wave
            floatx4 acc[4] = {};
            {
                const f16* br0 = &bl0[par][hrow][kq * 128 + quad * 8];
                const f16* br1 = &bl1[par][hrow][kq * 64 + quad * 8];
#pragma unroll
                for (int kk = 0; kk < 4; ++kk) {
                    const half8 bv = *(const half8*)(br0 + kk * 32);
#pragma unroll
                    for (int gt = 0; gt < 4; ++gt)
                        acc[gt] = __builtin_amdgcn_mfma_f32_16x16x32_f16(
                            ah[gt][kk], bv, acc[gt], 0, 0, 0);
                }
#pragma unroll
                for (int kk = 0; kk < 2; ++kk) {
                    const half8 bv = *(const half8*)(br1 + kk * 32);
#pragma unroll
                    for (int gt = 0; gt < 4; ++gt)
                        acc[gt] = __builtin_amdgcn_mfma_f32_16x16x32_f16(
                            ai[gt][kk], bv, acc[gt], 0, 0, 0);
                }
            }
            if (lm < 8)
#pragma unroll
                for (int gt = 0; gt < 4; ++gt)
#pragma unroll
                    for (int r = 0; r < 4; ++r)
                        glp[ug][kq][gt][quad * 4 + r][lm] = acc[gt][r];
            __syncthreads();
            // ---- gates (256 threads) + full-line ring store
            if (tid < 256) {
                float g4[4];
#pragma unroll
                for (int g = 0; g < 4; ++g) {
                    float s = bias[g];
#pragma unroll
                    for (int q = 0; q < 4; ++q) s += glp[gug][q][g][gjj][gb];
                    g4[g] = s;
                }
                const float hn = lstm_cell(g4[0], g4[1], g4[2], g4[3], c);
                const float ho = __shfl_xor(hn, 1);
                if (!(gj & 1)) {
                    union { f16 h[2]; uint32_t u; } pk;
                    pk.h[0] = (f16)hn; pk.h[1] = (f16)ho;
                    ast(ring + (size_t)(t & 3) * 2048 + gb * 256 + wgm * 16 + (gj >> 1),
                        pk.u);
                }
            }
            __syncthreads();                   // drains ring stores (vmcnt 0)
            if (tid == 0) ast(myF, (uint32_t)(t + 1));
        }
    } else {
        half8 ah[4][4], ai[4][4];
        {
#pragma unroll
            for (int gt = 0; gt < 4; ++gt) {
                const f16* wr = Whh1 + (size_t)(gt * 512 + ub + lm) * H_
                              + kq * 128 + quad * 8;
                const f16* xr = Wih1 + (size_t)(gt * 512 + ub + lm) * H_
                              + kq * 128 + quad * 8;
#pragma unroll
                for (int kk = 0; kk < 4; ++kk) {
                    ah[gt][kk] = *(const half8*)(wr + kk * 32);
                    ai[gt][kk] = *(const half8*)(xr + kk * 32);
                }
            }
        }
        for (int t = 0; t < T_; ++t) {
            const int par = t & 1;
            // ---- poll: own >= t, L0 >= t+1 (h0[t] published)
            if (wave == 0) {
                const uint32_t tgt = pollOwn ? (uint32_t)t : (uint32_t)(t + 1);
                uint32_t v = ald(fpp);
                while (!__all((int)(v >= tgt))) {
                    __builtin_amdgcn_s_sleep(1);
                    v = ald(fpp);
                }
            }
            __syncthreads();
            // ---- bulk gather h1[t-1] + h0[t]: 4 u64/thread, coalesced
            {
                const u64* sp1 = ringu + (size_t)((t + 3) & 3) * 1024;
                const u64* sp0 = crossu + (size_t)(t & 3) * 1024;
                const u64 a0 = ald64(sp1 + tid);
                const u64 a1 = ald64(sp1 + 512 + tid);
                const u64 c0 = ald64(sp0 + tid);
                const u64 c1 = ald64(sp0 + 512 + tid);
                *(u64*)&bl0[par][tid >> 7][(tid & 127) * 4] = a0;
                *(u64*)&bl0[par][(tid >> 7) + 4][(tid & 127) * 4] = a1;
                *(u64*)&bl1[par][tid >> 7][(tid & 127) * 4] = c0;
                *(u64*)&bl1[par][(tid >> 7) + 4][(tid & 127) * 4] = c1;
            }
            __syncthreads();
            // ---- MFMA: 16 Whh1 + 16 Wih1 per wave
            floatx4 acc[4] = {};
            {
                const f16* br0 = &bl0[par][hrow][kq * 128 + quad * 8];
                const f16* br1 = &bl1[par][hrow][kq * 128 + quad * 8];
#pragma unroll
                for (int kk = 0; kk < 4; ++kk) {
                    const half8 b0v = *(const half8*)(br0 + kk * 32);
                    const half8 b1v = *(const half8*)(br1 + kk * 32);
#pragma unroll
                    for (int gt = 0; gt < 4; ++gt) {
                        acc[gt] = __builtin_amdgcn_mfma_f32_16x16x32_f16(
                            ah[gt][kk], b0v, acc[gt], 0, 0, 0);
                        acc[gt] = __builtin_amdgcn_mfma_f32_16x16x32_f16(
                            ai[gt][kk], b1v, acc[gt], 0, 0, 0);
                    }
                }
            }
            if (lm < 8)
#pragma unroll
                for (int gt = 0; gt < 4; ++gt)
#pragma unroll
                    for (int r = 0; r < 4; ++r)
                        glp[ug][kq][gt][quad * 4 + r][lm] = acc[gt][r];
            __syncthreads();
            if (tid < 256) {
                float g4[4];
#pragma unroll
                for (int g = 0; g < 4; ++g) {
                    float s = bias[g];
#pragma unroll
                    for (int q = 0; q < 4; ++q) s += glp[gug][q][g][gjj][gb];
                    g4[g] = s;
                }
                const float hn = lstm_cell(g4[0], g4[1], g4[2], g4[3], c);
                const float ho = __shfl_xor(hn, 1);
                if (!(gj & 1)) {
                    union { f16 h[2]; uint32_t u; } pk;
                    pk.h[0] = (f16)hn; pk.h[1] = (f16)ho;
                    ast(ring + (size_t)(t & 3) * 2048 + gb * 256 + wgm * 16 + (gj >> 1),
                        pk.u);
                }
                if (t == T_ - 1)
                    dout[(size_t)(b0 + gb) * H_ + wgm * 32 + gj] = hn;
            }
            __syncthreads();                   // drains ring stores
            if (tid == 0) ast(myF, (uint32_t)(t + 1));
        }
    }
}

// ------------------------------------------------------------ launcher ------
extern "C" void kernel_launch(void* const* d_in, const int* in_sizes, int n_in,
                              void* d_out, int out_size, void* d_ws, size_t ws_size,
                              hipStream_t stream) {
    const float* x    = (const float*)d_in[0];
    const float* Wih0 = (const float*)d_in[1];
    const float* Whh0 = (const float*)d_in[2];
    const float* bih0 = (const float*)d_in[3];
    const float* bhh0 = (const float*)d_in[4];
    const float* mih0 = (const float*)d_in[5];
    const float* mhh0 = (const float*)d_in[6];
    const float* Wih1 = (const float*)d_in[7];
    const float* Whh1 = (const float*)d_in[8];
    const float* bih1 = (const float*)d_in[9];
    const float* bhh1 = (const float*)d_in[10];
    const float* mih1 = (const float*)d_in[11];
    const float* mhh1 = (const float*)d_in[12];

    char* ws = (char*)d_ws;
    uint32_t* flags = (uint32_t*)(ws + OFF_FLAGS);
    uint32_t* h0b = (uint32_t*)(ws + OFF_H0B);
    uint32_t* h1b = (uint32_t*)(ws + OFF_H1B);
    f16*   wih0 = (f16*)(ws + OFF_WIH0);
    f16*   whh0 = (f16*)(ws + OFF_WHH0);
    f16*   wih1 = (f16*)(ws + OFF_WIH1);
    f16*   whh1 = (f16*)(ws + OFF_WHH1);
    float* bs0  = (float*)(ws + OFF_B0);
    float* bs1  = (float*)(ws + OFF_B1);
    float* out  = (float*)d_out;

    hipMemsetAsync(ws, 0, ZERO_BYTES, stream);   // flags + rings must start 0

    k_maskw<<<512,  256, 0, stream>>>(Wih0, mih0, wih0, G_ * DIN_ / 4);
    k_maskw<<<1024, 256, 0, stream>>>(Whh0, mhh0, whh0, G_ * H_ / 4);
    k_maskw<<<1024, 256, 0, stream>>>(Wih1, mih1, wih1, G_ * H_ / 4);
    k_maskw<<<1024, 256, 0, stream>>>(Whh1, mhh1, whh1, G_ * H_ / 4);
    k_bias<<<8, 256, 0, stream>>>(bih0, bhh0, bs0);
    k_bias<<<8, 256, 0, stream>>>(bih1, bhh1, bs1);

    fused_rnn<<<256, 512, 0, stream>>>(x, wih0, whh0, bs0, wih1, whh1, bs1,
                                       out, h0b, h1b, flags);

    (void)in_sizes; (void)n_in; (void)out_size; (void)ws_size;
}